// Round 3
// baseline (715.362 us; speedup 1.0000x reference)
//
#include <hip/hip_runtime.h>
#include <hip/hip_bf16.h>

#define NNODES 100000
#define NEDGES 3200000
#define DIM    512
#define GF     4
#define HD     128

typedef __bf16 bf16x8 __attribute__((ext_vector_type(8)));
typedef float  f32x4  __attribute__((ext_vector_type(4)));

// ---------------- runtime dtype dispatch helpers ----------------
__device__ __forceinline__ float ldF(const void* p, size_t i, int isF32) {
    return isF32 ? ((const float*)p)[i]
                 : __bfloat162float(((const __hip_bfloat16*)p)[i]);
}
__device__ __forceinline__ void stF(void* p, size_t i, float v, int isF32) {
    if (isF32) ((float*)p)[i] = v;
    else       ((__hip_bfloat16*)p)[i] = __float2bfloat16(v);
}
__device__ __forceinline__ long long ldI(const void* p, size_t i, int isI64) {
    return isI64 ? ((const long long*)p)[i] : (long long)((const int*)p)[i];
}
// load 8 consecutive float-elements starting at elemOff, return as bf16x8
__device__ __forceinline__ bf16x8 ld8(const void* base, size_t elemOff, int isF32) {
    if (isF32) {
        const float* p = (const float*)base + elemOff;
        f32x4 a = *(const f32x4*)p;
        f32x4 b = *(const f32x4*)(p + 4);
        bf16x8 r;
        r[0] = (__bf16)a[0]; r[1] = (__bf16)a[1]; r[2] = (__bf16)a[2]; r[3] = (__bf16)a[3];
        r[4] = (__bf16)b[0]; r[5] = (__bf16)b[1]; r[6] = (__bf16)b[2]; r[7] = (__bf16)b[3];
        return r;
    }
    return *(const bf16x8*)((const __hip_bfloat16*)base + elemOff);
}

// ---------------- D0: detect dtypes from buffer contents ----------------
// flags[0]=1 if float arrays are f32 (else bf16); flags[1]=1 if index arrays are i64.
__global__ void detect_kernel(const unsigned short* __restrict__ featU16,
                              const int* __restrict__ srcI32,
                              int* __restrict__ flags) {
    __shared__ int sF, sI;
    if (threadIdx.x == 0) { sF = 0; sI = 0; }
    __syncthreads();
    int cntF = 0, cntI = 0;
    for (int i = threadIdx.x; i < 8192; i += 256) {
        unsigned short u = featU16[i];
        int e = (u >> 7) & 0xFF;         // bf16 exponent field
        if (e >= 0xE0) cntF++;           // |x| >= 2^97: impossible for N(0,1) bf16
        if ((i & 1) && srcI32[i] != 0) cntI++;  // odd i32 word nonzero => not i64 highs
    }
    atomicAdd(&sF, cntF);
    atomicAdd(&sI, cntI);
    __syncthreads();
    if (threadIdx.x == 0) {
        flags[0] = (sF > 20) ? 1 : 0;
        flags[1] = (sI == 0) ? 1 : 0;
    }
}

// ---------- P1: Wt[col][d] = att[g,d] * W_lin[g,d,h]  (col=g*128+h), bf16 ----------
__global__ void prep_kernel(const void* __restrict__ att,
                            const void* __restrict__ W_lin,
                            __hip_bfloat16* __restrict__ Wt,
                            const int* __restrict__ flags) {
    const int isF32 = flags[0];
    int t = blockIdx.x * blockDim.x + threadIdx.x;   // 0..2047 = (g,d)
    int g = t >> 9, d = t & 511;
    float a = ldF(att, (size_t)g * DIM + d, isF32);
    size_t wbase = ((size_t)g * DIM + d) * HD;
    __hip_bfloat16* wt = Wt + (size_t)(g * HD) * DIM + d;
    for (int h = 0; h < HD; ++h) {
        float w = ldF(W_lin, wbase + h, isF32);
        wt[(size_t)h * DIM] = __float2bfloat16(a * w);   // coalesced across lanes (d)
    }
}

// ---------- P2: cb[g] = b_al+b_ar + sum_h b_lin*(w_al+w_ar) ----------
__global__ void bias_kernel(const void* b_lin, const void* w_al, const void* b_al,
                            const void* w_ar, const void* b_ar,
                            float* cb, const int* __restrict__ flags) {
    const int isF32 = flags[0];
    int g = threadIdx.x;
    if (g < GF) {
        float s = ldF(b_al, g, isF32) + ldF(b_ar, g, isF32);
        for (int h = 0; h < HD; ++h) {
            float bl = ldF(b_lin, g * HD + h, isF32);
            s += bl * (ldF(w_al, g * HD + h, isF32) + ldF(w_ar, g * HD + h, isF32));
        }
        cb[g] = s;
    }
}

// ---------- GEMM: hidden = feat @ Wt^T (+b_lin), fused a_l/a_r epilogue ----------
__global__ __launch_bounds__(256, 2) void gemm_kernel(
        const void* __restrict__ feat,
        const __hip_bfloat16* __restrict__ Wt,
        const void* __restrict__ b_lin,
        const void* __restrict__ w_al,
        const void* __restrict__ w_ar,
        void* __restrict__ out_hidden,
        float* __restrict__ a_l, float* __restrict__ a_r,
        const int* __restrict__ flags) {
    __shared__ __attribute__((aligned(16))) __hip_bfloat16 lds[8192]; // As[128][32]|Bs[128][32]
    const int isF32 = flags[0];

    const int tid  = threadIdx.x;
    const int lane = tid & 63;
    const int wave = tid >> 6;
    const int q    = lane >> 4;
    const int lm   = lane & 15;
    const int waveM = wave >> 1;           // 2x2 wave grid, each 64x64
    const int waveN = wave & 1;
    const int g = blockIdx.y;              // 128-col tile == factor g
    const int rowBase = blockIdx.x * 128;

    // staging: chunk c -> row c>>2, k-off (c&3)*8 ; lds element off = c*8
    const int c = tid;
    const int koff = (c & 3) * 8;
    size_t ar0 = (size_t)min(rowBase + (c >> 2), NNODES - 1) * DIM + koff;
    size_t ar1 = (size_t)min(rowBase + (c >> 2) + 64, NNODES - 1) * DIM + koff;
    const __hip_bfloat16* gB0 = Wt + (size_t)(g * HD + (c >> 2)) * DIM + koff;
    const __hip_bfloat16* gB1 = Wt + (size_t)(g * HD + (c >> 2) + 64) * DIM + koff;
    __hip_bfloat16* lA0 = lds + c * 8;
    __hip_bfloat16* lA1 = lds + (c + 256) * 8;
    __hip_bfloat16* lB0 = lds + 4096 + c * 8;
    __hip_bfloat16* lB1 = lds + 4096 + (c + 256) * 8;

    f32x4 acc[4][4];
#pragma unroll
    for (int mi = 0; mi < 4; ++mi)
#pragma unroll
        for (int ni = 0; ni < 4; ++ni) {
            f32x4 z = {0.f, 0.f, 0.f, 0.f};
            acc[mi][ni] = z;
        }

    int aoff[4], boff[4];
#pragma unroll
    for (int mi = 0; mi < 4; ++mi) aoff[mi] = (waveM * 64 + mi * 16 + lm) * 32 + q * 8;
#pragma unroll
    for (int ni = 0; ni < 4; ++ni) boff[ni] = 4096 + (waveN * 64 + ni * 16 + lm) * 32 + q * 8;

    for (int ko = 0; ko < DIM / 32; ++ko) {
        bf16x8 va0 = ld8(feat, ar0, isF32);
        bf16x8 va1 = ld8(feat, ar1, isF32);
        bf16x8 vb0 = *(const bf16x8*)gB0;
        bf16x8 vb1 = *(const bf16x8*)gB1;
        ar0 += 32; ar1 += 32; gB0 += 32; gB1 += 32;

        __syncthreads();                       // all waves done reading prev tile
        *(bf16x8*)lA0 = va0;
        *(bf16x8*)lA1 = va1;
        *(bf16x8*)lB0 = vb0;
        *(bf16x8*)lB1 = vb1;
        __syncthreads();                       // stores visible to all waves

        bf16x8 af[4], bfr[4];
#pragma unroll
        for (int mi = 0; mi < 4; ++mi) af[mi] = *(const bf16x8*)(lds + aoff[mi]);
#pragma unroll
        for (int ni = 0; ni < 4; ++ni) bfr[ni] = *(const bf16x8*)(lds + boff[ni]);
#pragma unroll
        for (int mi = 0; mi < 4; ++mi)
#pragma unroll
            for (int ni = 0; ni < 4; ++ni)
                acc[mi][ni] = __builtin_amdgcn_mfma_f32_16x16x32_bf16(
                    af[mi], bfr[ni], acc[mi][ni], 0, 0, 0);
    }

    // epilogue: per-column weights (col = waveN*64 + ni*16 + lm within g)
    float wal[4], war[4], blin[4];
#pragma unroll
    for (int ni = 0; ni < 4; ++ni) {
        int col = waveN * 64 + ni * 16 + lm;
        wal[ni]  = ldF(w_al,  g * HD + col, isF32);
        war[ni]  = ldF(w_ar,  g * HD + col, isF32);
        blin[ni] = ldF(b_lin, g * HD + col, isF32);
    }
    float sal[4][4], sar[4][4];
#pragma unroll
    for (int mi = 0; mi < 4; ++mi)
#pragma unroll
        for (int r = 0; r < 4; ++r) {
            float sa = 0.f, sr = 0.f;
#pragma unroll
            for (int ni = 0; ni < 4; ++ni) {
                float v = acc[mi][ni][r];
                sa += v * wal[ni];
                sr += v * war[ni];
            }
            sal[mi][r] = sa; sar[mi][r] = sr;
        }
    // reduce across the 16 lm lanes (masks 1,2,4,8 stay inside the 16-group)
#pragma unroll
    for (int off = 1; off < 16; off <<= 1)
#pragma unroll
        for (int mi = 0; mi < 4; ++mi)
#pragma unroll
            for (int r = 0; r < 4; ++r) {
                sal[mi][r] += __shfl_xor(sal[mi][r], off, 64);
                sar[mi][r] += __shfl_xor(sar[mi][r], off, 64);
            }

#pragma unroll
    for (int mi = 0; mi < 4; ++mi)
#pragma unroll
        for (int r = 0; r < 4; ++r) {
            int row = rowBase + waveM * 64 + mi * 16 + q * 4 + r;  // C/D: row=q*4+reg
            if (row < NNODES) {
#pragma unroll
                for (int ni = 0; ni < 4; ++ni) {
                    int col = g * HD + waveN * 64 + ni * 16 + lm;  // C/D: col=lane&15
                    stF(out_hidden, (size_t)row * DIM + col,
                        acc[mi][ni][r] + blin[ni], isF32);
                }
                if (lm == 0) {
                    atomicAdd(&a_l[g * NNODES + row], sal[mi][r]);
                    atomicAdd(&a_r[g * NNODES + row], sar[mi][r]);
                }
            }
        }
}

// ---------- edges: factors = sigmoid(a_l[src] + a_r[dst] + cb) ----------
__global__ __launch_bounds__(256) void edge_kernel(
        const void* __restrict__ src, const void* __restrict__ dst,
        const float* __restrict__ a_l, const float* __restrict__ a_r,
        const float* __restrict__ cb, void* __restrict__ out,
        const int* __restrict__ flags) {
    const int isF32 = flags[0];
    const int isI64 = flags[1];
    int e = blockIdx.x * 256 + threadIdx.x;
    if (e >= NEDGES) return;
    long long s = ldI(src, e, isI64);
    long long d = ldI(dst, e, isI64);
    const size_t base = (size_t)NNODES * DIM;
#pragma unroll
    for (int g = 0; g < GF; ++g) {
        float x = a_l[g * NNODES + s] + a_r[g * NNODES + d] + cb[g];
        float f = 1.0f / (1.0f + __expf(-x));   // SIGMA = 1.0
        stF(out, base + (size_t)g * NEDGES + e, f, isF32);
    }
}

extern "C" void kernel_launch(void* const* d_in, const int* in_sizes, int n_in,
                              void* d_out, int out_size, void* d_ws, size_t ws_size,
                              hipStream_t stream) {
    const void* feat  = d_in[0];
    const void* src   = d_in[1];
    const void* dst   = d_in[2];
    const void* att   = d_in[3];
    const void* W_lin = d_in[4];
    const void* b_lin = d_in[5];
    const void* w_al  = d_in[6];
    const void* b_al  = d_in[7];
    const void* w_ar  = d_in[8];
    const void* b_ar  = d_in[9];

    char* ws = (char*)d_ws;
    int*   flags = (int*)ws;                            // 8 B
    float* cb    = (float*)(ws + 16);                   // 16 B
    __hip_bfloat16* Wt = (__hip_bfloat16*)(ws + 1024);  // 512*512*2 = 524288 B
    float* a_l = (float*)(ws + 1024 + 524288);          // 1.6 MB
    float* a_r = (float*)(ws + 1024 + 524288 + 1600000);// 1.6 MB  (total ~3.73 MB)

    hipMemsetAsync(a_l, 0, 3200000, stream);            // zero a_l + a_r (contiguous)
    detect_kernel<<<1, 256, 0, stream>>>((const unsigned short*)feat, (const int*)src, flags);
    prep_kernel<<<8, 256, 0, stream>>>(att, W_lin, Wt, flags);
    bias_kernel<<<1, 64, 0, stream>>>(b_lin, w_al, b_al, w_ar, b_ar, cb, flags);

    gemm_kernel<<<dim3((NNODES + 127) / 128, GF), 256, 0, stream>>>(
        feat, Wt, b_lin, w_al, w_ar, d_out, a_l, a_r, flags);
    edge_kernel<<<NEDGES / 256, 256, 0, stream>>>(
        src, dst, a_l, a_r, cb, d_out, flags);
}